// Round 5
// baseline (96.845 us; speedup 1.0000x reference)
//
#include <hip/hip_runtime.h>
#include <cstdint>
#include <cstddef>

typedef __attribute__((ext_vector_type(4))) short short4v;
typedef __attribute__((ext_vector_type(4))) float float4v;

#define C_IN  64
#define NB    2
#define NPTS  32768   // 32*32*32
#define MPTS  4096    // 16*16*16
#define LOG2E 1.44269504088896340736f
#define KT    64              // keys per staged tile
#define NTILE (MPTS / KT)     // 64
#define QTILES (NPTS / 32)    // 1024 q-tiles of 32 per batch

__device__ __forceinline__ unsigned short f2bf_rne(float f) {
  unsigned int u = __builtin_bit_cast(unsigned int, f);
  u += 0x7fffu + ((u >> 16) & 1u);
  return (unsigned short)(u >> 16);
}

__device__ __forceinline__ short4v pack_bf16_trunc(float a0, float a1, float a2, float a3) {
  unsigned int u0 = __builtin_amdgcn_perm(__builtin_bit_cast(unsigned int, a1),
                                          __builtin_bit_cast(unsigned int, a0), 0x07060302u);
  unsigned int u1 = __builtin_amdgcn_perm(__builtin_bit_cast(unsigned int, a3),
                                          __builtin_bit_cast(unsigned int, a2), 0x07060302u);
  union { unsigned int u[2]; short4v s; } r;
  r.u[0] = u0; r.u[1] = u1;
  return r.s;
}

__device__ __forceinline__ short4v pack_bf16_rne(float a0, float a1, float a2, float a3) {
  short4v s;
  s[0] = (short)f2bf_rne(a0); s[1] = (short)f2bf_rne(a1);
  s[2] = (short)f2bf_rne(a2); s[3] = (short)f2bf_rne(a3);
  return s;
}

__device__ __forceinline__ void gl_lds16(const unsigned short* g, unsigned short* l) {
  __builtin_amdgcn_global_load_lds(
      (const __attribute__((address_space(1))) void*)g,
      (__attribute__((address_space(3))) void*)l, 16, 0, 0);
}

// ---------------------------------------------------------------------------
// Fragment layouts (lane-major, bank-conflict-free ds_read_b64):
// A 16x16 bf16 MFMA A-fragment stores element (row c, k) at
//   pos = ((k>>2)*16 + c)*4 + (k&3)   -> lane (l4,col) reads 8B at lane*8.
// phi_f: [B][M/16][256]  (row = key, k = channel; log2e folded; ch 8..15 zero)
// g_f:   [B][M/16][2][256] (row = channel within half, k = key)
// ---------------------------------------------------------------------------

__device__ void pool_body(int idx, const float* __restrict__ x,
                          const float* __restrict__ w_phi,
                          const float* __restrict__ w_g,
                          unsigned short* __restrict__ phi_f,
                          unsigned short* __restrict__ g_f) {
  int cg = idx >> 13;          // 0..4: 0 -> phi ch0..7, 1..4 -> g ch (cg-1)*8..+7
  int bm = idx & 8191;
  int b = bm >> 12, m = bm & 4095;
  int md = m >> 8, mh = (m >> 4) & 15, mw = m & 15;
  const float* xb = x + (size_t)b * C_IN * NPTS
                  + ((md * 2) * 1024 + (mh * 2) * 32 + (mw * 2));
  const float* wbase = (cg == 0) ? w_phi : (w_g + (cg - 1) * 8 * C_IN);

  float acc[8][8];
#pragma unroll
  for (int o = 0; o < 8; ++o)
#pragma unroll
    for (int p = 0; p < 8; ++p) acc[o][p] = 0.f;

#pragma unroll 4
  for (int cc = 0; cc < C_IN; ++cc) {
    const float* xp = xb + (size_t)cc * NPTS;
    float2 p01 = *(const float2*)(xp + 0);
    float2 p23 = *(const float2*)(xp + 32);
    float2 p45 = *(const float2*)(xp + 1024);
    float2 p67 = *(const float2*)(xp + 1056);
#pragma unroll
    for (int o = 0; o < 8; ++o) {
      float wv = wbase[o * C_IN + cc];
      acc[o][0] = fmaf(wv, p01.x, acc[o][0]);
      acc[o][1] = fmaf(wv, p01.y, acc[o][1]);
      acc[o][2] = fmaf(wv, p23.x, acc[o][2]);
      acc[o][3] = fmaf(wv, p23.y, acc[o][3]);
      acc[o][4] = fmaf(wv, p45.x, acc[o][4]);
      acc[o][5] = fmaf(wv, p45.y, acc[o][5]);
      acc[o][6] = fmaf(wv, p67.x, acc[o][6]);
      acc[o][7] = fmaf(wv, p67.y, acc[o][7]);
    }
  }
  float mx[8];
#pragma unroll
  for (int o = 0; o < 8; ++o) {
    mx[o] = fmaxf(fmaxf(fmaxf(acc[o][0], acc[o][1]), fmaxf(acc[o][2], acc[o][3])),
                  fmaxf(fmaxf(acc[o][4], acc[o][5]), fmaxf(acc[o][6], acc[o][7])));
  }
  int kt16 = m >> 4, kr = m & 15;
  if (cg == 0) {
    // phi fragment: (row=key kr, k=channel c): pos = ((c>>2)*16 + kr)*4 + (c&3)
    size_t fb = ((size_t)b * 256 + kt16) * 256;
#pragma unroll
    for (int g2 = 0; g2 < 2; ++g2) {   // channel quads 0..1 (ch 0..7)
      unsigned int u0 = (unsigned int)f2bf_rne(mx[g2 * 4 + 0] * LOG2E)
                      | ((unsigned int)f2bf_rne(mx[g2 * 4 + 1] * LOG2E) << 16);
      unsigned int u1 = (unsigned int)f2bf_rne(mx[g2 * 4 + 2] * LOG2E)
                      | ((unsigned int)f2bf_rne(mx[g2 * 4 + 3] * LOG2E) << 16);
      *(uint2*)&phi_f[fb + (g2 * 16 + kr) * 4] = make_uint2(u0, u1);
    }
#pragma unroll
    for (int g2 = 2; g2 < 4; ++g2) {   // zero-pad ch 8..15
      *(uint2*)&phi_f[fb + (g2 * 16 + kr) * 4] = make_uint2(0u, 0u);
    }
  } else {
    int gc0 = (cg - 1) * 8;
#pragma unroll
    for (int o = 0; o < 8; ++o) {
      int c = gc0 + o;
      int half = c >> 4, c15 = c & 15;
      size_t base = (((size_t)b * 256 + kt16) * 2 + half) * 256;
      // g fragment: (row=channel c15, k=key kr): pos = ((kr>>2)*16 + c15)*4 + (kr&3)
      g_f[base + ((kr >> 2) * 16 + c15) * 4 + (kr & 3)] = f2bf_rne(mx[o]);
    }
  }
}

__device__ void theta_body(int idx, const float* __restrict__ x,
                           const float* __restrict__ w_theta,
                           unsigned short* __restrict__ theta_pad) {
  int b = idx >> 15, n = idx & 32767;
  const float* xb = x + (size_t)b * C_IN * NPTS + n;
  float t[8];
#pragma unroll
  for (int o = 0; o < 8; ++o) t[o] = 0.f;
#pragma unroll 4
  for (int cc = 0; cc < C_IN; ++cc) {
    float xv = xb[(size_t)cc * NPTS];
#pragma unroll
    for (int o = 0; o < 8; ++o) t[o] = fmaf(w_theta[o * C_IN + cc], xv, t[o]);
  }
  unsigned int w0 = (unsigned int)f2bf_rne(t[0]) | ((unsigned int)f2bf_rne(t[1]) << 16);
  unsigned int w1 = (unsigned int)f2bf_rne(t[2]) | ((unsigned int)f2bf_rne(t[3]) << 16);
  unsigned int w2 = (unsigned int)f2bf_rne(t[4]) | ((unsigned int)f2bf_rne(t[5]) << 16);
  unsigned int w3 = (unsigned int)f2bf_rne(t[6]) | ((unsigned int)f2bf_rne(t[7]) << 16);
  uint4* dst = (uint4*)(theta_pad + ((size_t)idx << 4));
  dst[0] = make_uint4(w0, w1, w2, w3);
  dst[1] = make_uint4(0u, 0u, 0u, 0u);
}

__global__ __launch_bounds__(256) void prep_fused(
    const float* __restrict__ x, const float* __restrict__ w_theta,
    const float* __restrict__ w_phi, const float* __restrict__ w_g,
    unsigned short* __restrict__ theta_pad,
    unsigned short* __restrict__ phi_f,
    unsigned short* __restrict__ g_f) {
  int gb = blockIdx.x;
  if (gb < 160) {
    pool_body(gb * 256 + threadIdx.x, x, w_phi, w_g, phi_f, g_f);
  } else {
    theta_body((gb - 160) * 256 + threadIdx.x, x, w_theta, theta_pad);
  }
}

// ---------------------------------------------------------------------------
// Pass 1: split-K flash attention partials (templated split factor).
// Grid (NPTS/128, NB*KS). LDS reads are lane-major contiguous (0 conflicts).
// ---------------------------------------------------------------------------
template <int KS>
__global__ __launch_bounds__(256) void attn_split(
    const unsigned short* __restrict__ theta_pad,
    const unsigned short* __restrict__ phi_f,
    const unsigned short* __restrict__ g_f,
    float4v* __restrict__ opart,
    float* __restrict__ lbuf) {
  __shared__ unsigned short s_phi[2][KT * 16];       // 2 KB per buf
  __shared__ unsigned short s_g[2][(KT / 16) * 512]; // 4 KB per buf

  int tid = threadIdx.x;
  int wid = tid >> 6, lane = tid & 63;
  int l4 = lane >> 4, col = lane & 15;
  int b = blockIdx.y / KS;
  int ks = blockIdx.y & (KS - 1);
  int qb = blockIdx.x * 128 + wid * 32;
  int t0 = ks * (NTILE / KS);
  int t1 = t0 + NTILE / KS;

  const unsigned short* tb = theta_pad + ((size_t)(b * NPTS + qb) << 4) + l4 * 4;
  short4v bt0 = *(const short4v*)(tb + (col << 4));
  short4v bt1 = *(const short4v*)(tb + ((16 + col) << 4));

  const unsigned short* phib = phi_f + (size_t)b * 256 * 256;
  const unsigned short* gb   = g_f + (size_t)b * 256 * 512;

  float4v acc00 = {0.f, 0.f, 0.f, 0.f}, acc01 = acc00, acc10 = acc00, acc11 = acc00;
  float lsum0 = 0.f, lsum1 = 0.f;

  gl_lds16(gb + (size_t)t0 * 2048 + wid * 512 + lane * 8, &s_g[0][wid * 512]);
  if (wid < 2)
    gl_lds16(phib + (size_t)t0 * 1024 + wid * 512 + lane * 8, &s_phi[0][wid * 512]);
  __syncthreads();

#pragma unroll 1
  for (int t = t0; t < t1; ++t) {
    int cur = t & 1;
    if (t + 1 < t1) {
      gl_lds16(gb + (size_t)(t + 1) * 2048 + wid * 512 + lane * 8,
               &s_g[cur ^ 1][wid * 512]);
      if (wid < 2)
        gl_lds16(phib + (size_t)(t + 1) * 1024 + wid * 512 + lane * 8,
                 &s_phi[cur ^ 1][wid * 512]);
    }

#pragma unroll
    for (int st = 0; st < 4; ++st) {
      // lane-major contiguous reads: lane i reads bytes [i*8, i*8+8)
      short4v pf = *(const short4v*)&s_phi[cur][st * 256 + lane * 4];
      short4v g0 = *(const short4v*)&s_g[cur][st * 512 + lane * 4];
      short4v g1 = *(const short4v*)&s_g[cur][st * 512 + 256 + lane * 4];

      float4v zero4 = {0.f, 0.f, 0.f, 0.f};
      float4v s0 = __builtin_amdgcn_mfma_f32_16x16x16bf16_1k(pf, bt0, zero4, 0, 0, 0);
      float4v s1 = __builtin_amdgcn_mfma_f32_16x16x16bf16_1k(pf, bt1, zero4, 0, 0, 0);

      float p00 = __builtin_amdgcn_exp2f(s0[0]);
      float p01 = __builtin_amdgcn_exp2f(s0[1]);
      float p02 = __builtin_amdgcn_exp2f(s0[2]);
      float p03 = __builtin_amdgcn_exp2f(s0[3]);
      float p10 = __builtin_amdgcn_exp2f(s1[0]);
      float p11 = __builtin_amdgcn_exp2f(s1[1]);
      float p12 = __builtin_amdgcn_exp2f(s1[2]);
      float p13 = __builtin_amdgcn_exp2f(s1[3]);
      lsum0 += (p00 + p01) + (p02 + p03);
      lsum1 += (p10 + p11) + (p12 + p13);
      short4v pb0 = pack_bf16_trunc(p00, p01, p02, p03);
      short4v pb1 = pack_bf16_trunc(p10, p11, p12, p13);

      acc00 = __builtin_amdgcn_mfma_f32_16x16x16bf16_1k(g0, pb0, acc00, 0, 0, 0);
      acc01 = __builtin_amdgcn_mfma_f32_16x16x16bf16_1k(g0, pb1, acc01, 0, 0, 0);
      acc10 = __builtin_amdgcn_mfma_f32_16x16x16bf16_1k(g1, pb0, acc10, 0, 0, 0);
      acc11 = __builtin_amdgcn_mfma_f32_16x16x16bf16_1k(g1, pb1, acc11, 0, 0, 0);
    }
    __syncthreads();
  }

  lsum0 += __shfl_xor(lsum0, 16, 64);
  lsum0 += __shfl_xor(lsum0, 32, 64);
  lsum1 += __shfl_xor(lsum1, 16, 64);
  lsum1 += __shfl_xor(lsum1, 32, 64);

  int qt = blockIdx.x * 4 + wid;
  size_t obase = (((size_t)(b * KS + ks) * QTILES + qt) * 4) * 64 + lane;
  opart[obase + 0 * 64] = acc00;
  opart[obase + 1 * 64] = acc01;
  opart[obase + 2 * 64] = acc10;
  opart[obase + 3 * 64] = acc11;
  if (lane < 32) {
    lbuf[((size_t)(b * KS + ks) * QTILES + qt) * 32 + lane] =
        (lane < 16) ? lsum0 : lsum1;
  }
}

// ---------------------------------------------------------------------------
// Pass 2: combine partials, normalize, w_o epilogue MFMA, gamma, residual.
// ---------------------------------------------------------------------------
template <int KS>
__global__ __launch_bounds__(256) void attn_combine(
    const float* __restrict__ x, const float* __restrict__ w_o,
    const float* __restrict__ gamma_p,
    const float4v* __restrict__ opart,
    const float* __restrict__ lbuf,
    float* __restrict__ out) {
  int tid = threadIdx.x;
  int wid = tid >> 6, lane = tid & 63;
  int l4 = lane >> 4, col = lane & 15;
  int b = blockIdx.y;
  int qt = blockIdx.x * 4 + wid;
  int qb = qt * 32;

  float gamma = gamma_p[0];

  short4v wo[4][2];
#pragma unroll
  for (int cot = 0; cot < 4; ++cot)
#pragma unroll
    for (int ksw = 0; ksw < 2; ++ksw) {
      const float* wp = w_o + (cot * 16 + col) * 32 + ksw * 16 + l4 * 4;
      wo[cot][ksw] = pack_bf16_rne(wp[0] * gamma, wp[1] * gamma,
                                   wp[2] * gamma, wp[3] * gamma);
    }

  float4v a0 = {0.f, 0.f, 0.f, 0.f}, a1 = a0, a2 = a0, a3 = a0;
  float ls0 = 0.f, ls1 = 0.f;
#pragma unroll
  for (int ks = 0; ks < KS; ++ks) {
    size_t ob = (((size_t)(b * KS + ks) * QTILES + qt) * 4) * 64 + lane;
    a0 += opart[ob + 0 * 64];
    a1 += opart[ob + 1 * 64];
    a2 += opart[ob + 2 * 64];
    a3 += opart[ob + 3 * 64];
    const float* lb = lbuf + ((size_t)(b * KS + ks) * QTILES + qt) * 32;
    ls0 += lb[col];
    ls1 += lb[col + 16];
  }
  float li0 = 1.0f / ls0;
  float li1 = 1.0f / ls1;

  short4v onb00 = pack_bf16_rne(a0[0] * li0, a0[1] * li0, a0[2] * li0, a0[3] * li0);
  short4v onb01 = pack_bf16_rne(a1[0] * li1, a1[1] * li1, a1[2] * li1, a1[3] * li1);
  short4v onb10 = pack_bf16_rne(a2[0] * li0, a2[1] * li0, a2[2] * li0, a2[3] * li0);
  short4v onb11 = pack_bf16_rne(a3[0] * li1, a3[1] * li1, a3[2] * li1, a3[3] * li1);

  float4v zero4 = {0.f, 0.f, 0.f, 0.f};
#pragma unroll
  for (int cot = 0; cot < 4; ++cot) {
#pragma unroll
    for (int nt = 0; nt < 2; ++nt) {
      short4v bfrag0 = nt ? onb01 : onb00;
      short4v bfrag1 = nt ? onb11 : onb10;
      float4v d = __builtin_amdgcn_mfma_f32_16x16x16bf16_1k(wo[cot][0], bfrag0, zero4, 0, 0, 0);
      d = __builtin_amdgcn_mfma_f32_16x16x16bf16_1k(wo[cot][1], bfrag1, d, 0, 0, 0);
      int n = qb + nt * 16 + col;
      size_t base = (size_t)(b * C_IN + cot * 16 + l4 * 4) * NPTS + n;
      const float* xp = x + base;
      float* op = out + base;
#pragma unroll
      for (int e = 0; e < 4; ++e) {
        op[(size_t)e * NPTS] = d[e] + xp[(size_t)e * NPTS];
      }
    }
  }
}

// ---------------------------------------------------------------------------
// Fallback single-pass attention (lane-major layouts) for small ws_size.
// ---------------------------------------------------------------------------
__global__ __launch_bounds__(256) void attn_mfma(
    const float* __restrict__ x, const float* __restrict__ w_o,
    const float* __restrict__ gamma_p,
    const unsigned short* __restrict__ theta_pad,
    const unsigned short* __restrict__ phi_f,
    const unsigned short* __restrict__ g_f,
    float* __restrict__ out) {
  __shared__ unsigned short s_phi[2][KT * 16];
  __shared__ unsigned short s_g[2][(KT / 16) * 512];

  int tid = threadIdx.x;
  int wid = tid >> 6, lane = tid & 63;
  int l4 = lane >> 4, col = lane & 15;
  int b = blockIdx.y;
  int qb = blockIdx.x * 128 + wid * 32;

  float gamma = gamma_p[0];

  const unsigned short* tb = theta_pad + ((size_t)(b * NPTS + qb) << 4) + l4 * 4;
  short4v bt0 = *(const short4v*)(tb + (col << 4));
  short4v bt1 = *(const short4v*)(tb + ((16 + col) << 4));

  short4v wo[4][2];
#pragma unroll
  for (int cot = 0; cot < 4; ++cot)
#pragma unroll
    for (int ksw = 0; ksw < 2; ++ksw) {
      const float* wp = w_o + (cot * 16 + col) * 32 + ksw * 16 + l4 * 4;
      wo[cot][ksw] = pack_bf16_rne(wp[0] * gamma, wp[1] * gamma,
                                   wp[2] * gamma, wp[3] * gamma);
    }

  const unsigned short* phib = phi_f + (size_t)b * 256 * 256;
  const unsigned short* gb   = g_f + (size_t)b * 256 * 512;

  float4v acc00 = {0.f, 0.f, 0.f, 0.f}, acc01 = acc00, acc10 = acc00, acc11 = acc00;
  float lsum0 = 0.f, lsum1 = 0.f;

  gl_lds16(gb + 0 * 2048 + wid * 512 + lane * 8, &s_g[0][wid * 512]);
  if (wid < 2)
    gl_lds16(phib + 0 * 1024 + wid * 512 + lane * 8, &s_phi[0][wid * 512]);
  __syncthreads();

#pragma unroll 1
  for (int t = 0; t < NTILE; ++t) {
    int cur = t & 1;
    if (t + 1 < NTILE) {
      gl_lds16(gb + (size_t)(t + 1) * 2048 + wid * 512 + lane * 8,
               &s_g[cur ^ 1][wid * 512]);
      if (wid < 2)
        gl_lds16(phib + (size_t)(t + 1) * 1024 + wid * 512 + lane * 8,
                 &s_phi[cur ^ 1][wid * 512]);
    }
#pragma unroll
    for (int st = 0; st < 4; ++st) {
      short4v pf = *(const short4v*)&s_phi[cur][st * 256 + lane * 4];
      short4v g0 = *(const short4v*)&s_g[cur][st * 512 + lane * 4];
      short4v g1 = *(const short4v*)&s_g[cur][st * 512 + 256 + lane * 4];

      float4v zero4 = {0.f, 0.f, 0.f, 0.f};
      float4v s0 = __builtin_amdgcn_mfma_f32_16x16x16bf16_1k(pf, bt0, zero4, 0, 0, 0);
      float4v s1 = __builtin_amdgcn_mfma_f32_16x16x16bf16_1k(pf, bt1, zero4, 0, 0, 0);

      float p00 = __builtin_amdgcn_exp2f(s0[0]);
      float p01 = __builtin_amdgcn_exp2f(s0[1]);
      float p02 = __builtin_amdgcn_exp2f(s0[2]);
      float p03 = __builtin_amdgcn_exp2f(s0[3]);
      float p10 = __builtin_amdgcn_exp2f(s1[0]);
      float p11 = __builtin_amdgcn_exp2f(s1[1]);
      float p12 = __builtin_amdgcn_exp2f(s1[2]);
      float p13 = __builtin_amdgcn_exp2f(s1[3]);
      lsum0 += (p00 + p01) + (p02 + p03);
      lsum1 += (p10 + p11) + (p12 + p13);
      short4v pb0 = pack_bf16_trunc(p00, p01, p02, p03);
      short4v pb1 = pack_bf16_trunc(p10, p11, p12, p13);

      acc00 = __builtin_amdgcn_mfma_f32_16x16x16bf16_1k(g0, pb0, acc00, 0, 0, 0);
      acc01 = __builtin_amdgcn_mfma_f32_16x16x16bf16_1k(g0, pb1, acc01, 0, 0, 0);
      acc10 = __builtin_amdgcn_mfma_f32_16x16x16bf16_1k(g1, pb0, acc10, 0, 0, 0);
      acc11 = __builtin_amdgcn_mfma_f32_16x16x16bf16_1k(g1, pb1, acc11, 0, 0, 0);
    }
    __syncthreads();
  }

  lsum0 += __shfl_xor(lsum0, 16, 64);
  lsum0 += __shfl_xor(lsum0, 32, 64);
  lsum1 += __shfl_xor(lsum1, 16, 64);
  lsum1 += __shfl_xor(lsum1, 32, 64);
  float li0 = 1.0f / lsum0;
  float li1 = 1.0f / lsum1;

  short4v onb00 = pack_bf16_rne(acc00[0] * li0, acc00[1] * li0, acc00[2] * li0, acc00[3] * li0);
  short4v onb01 = pack_bf16_rne(acc01[0] * li1, acc01[1] * li1, acc01[2] * li1, acc01[3] * li1);
  short4v onb10 = pack_bf16_rne(acc10[0] * li0, acc10[1] * li0, acc10[2] * li0, acc10[3] * li0);
  short4v onb11 = pack_bf16_rne(acc11[0] * li1, acc11[1] * li1, acc11[2] * li1, acc11[3] * li1);

  float4v zero4 = {0.f, 0.f, 0.f, 0.f};
#pragma unroll
  for (int cot = 0; cot < 4; ++cot) {
#pragma unroll
    for (int nt = 0; nt < 2; ++nt) {
      short4v bfrag0 = nt ? onb01 : onb00;
      short4v bfrag1 = nt ? onb11 : onb10;
      float4v d = __builtin_amdgcn_mfma_f32_16x16x16bf16_1k(wo[cot][0], bfrag0, zero4, 0, 0, 0);
      d = __builtin_amdgcn_mfma_f32_16x16x16bf16_1k(wo[cot][1], bfrag1, d, 0, 0, 0);
      int n = qb + nt * 16 + col;
      size_t base = (size_t)(b * C_IN + cot * 16 + l4 * 4) * NPTS + n;
      const float* xp = x + base;
      float* op = out + base;
#pragma unroll
      for (int e = 0; e < 4; ++e) {
        op[(size_t)e * NPTS] = d[e] + xp[(size_t)e * NPTS];
      }
    }
  }
}

extern "C" void kernel_launch(void* const* d_in, const int* in_sizes, int n_in,
                              void* d_out, int out_size, void* d_ws, size_t ws_size,
                              hipStream_t stream) {
  const float* x       = (const float*)d_in[0];
  const float* w_theta = (const float*)d_in[1];
  const float* w_phi   = (const float*)d_in[2];
  const float* w_g     = (const float*)d_in[3];
  const float* w_o     = (const float*)d_in[4];
  const float* gamma   = (const float*)d_in[5];
  float* out = (float*)d_out;

  char* ws = (char*)d_ws;
  unsigned short* theta_pad = (unsigned short*)ws;  ws += (size_t)NB * NPTS * 16 * 2;  // 2 MB
  unsigned short* phi_f     = (unsigned short*)ws;  ws += (size_t)NB * 256 * 256 * 2;  // 256 KB
  unsigned short* g_f       = (unsigned short*)ws;  ws += (size_t)NB * 256 * 512 * 2;  // 512 KB
  size_t base_need = (size_t)(ws - (char*)d_ws);
  float4v* opart = (float4v*)ws;
  size_t opart4 = (size_t)NB * 4 * QTILES * 4 * 64 * sizeof(float4v);   // 33.5 MB
  size_t opart2 = (size_t)NB * 2 * QTILES * 4 * 64 * sizeof(float4v);   // 16.8 MB
  size_t lbuf4  = (size_t)NB * 4 * QTILES * 32 * sizeof(float);         // 1 MB
  size_t lbuf2  = (size_t)NB * 2 * QTILES * 32 * sizeof(float);
  size_t need4 = base_need + opart4 + lbuf4;
  size_t need2 = base_need + opart2 + lbuf2;

  prep_fused<<<dim3(416), dim3(256), 0, stream>>>(
      x, w_theta, w_phi, w_g, theta_pad, phi_f, g_f);

  if (ws_size >= need4) {
    float* lbuf = (float*)((char*)opart + opart4);
    attn_split<4><<<dim3(NPTS / 128, NB * 4), dim3(256), 0, stream>>>(
        theta_pad, phi_f, g_f, opart, lbuf);
    attn_combine<4><<<dim3(NPTS / 128, NB), dim3(256), 0, stream>>>(
        x, w_o, gamma, opart, lbuf, out);
  } else if (ws_size >= need2) {
    float* lbuf = (float*)((char*)opart + opart2);
    attn_split<2><<<dim3(NPTS / 128, NB * 2), dim3(256), 0, stream>>>(
        theta_pad, phi_f, g_f, opart, lbuf);
    attn_combine<2><<<dim3(NPTS / 128, NB), dim3(256), 0, stream>>>(
        x, w_o, gamma, opart, lbuf, out);
  } else if (ws_size >= base_need) {
    attn_mfma<<<dim3(NPTS / 128, NB), dim3(256), 0, stream>>>(
        x, w_o, gamma, theta_pad, phi_f, g_f, out);
  }
}